// Round 11
// baseline (3966.674 us; speedup 1.0000x reference)
//
#include <hip/hip_runtime.h>

#define NTHR  256
#define F     59
#define K0    29
#define NB    15
#define B     131072
#define RPB   64                 // rows per block
#define NBLK  (B / RPB)          // 2048 blocks
#define NSLC  32                 // f64 atomic slices; 16B slot per (feature,slice)

// d_ws layout: acc[NB][F][NSLC][2] doubles, then hB[F][B] floats.
// (hA lives in d_out, dead until the final kernel.)
#define ACC_PER_LAYER (F * NSLC * 2)            // 3776 doubles / layer
#define ACC_TOTAL     (NB * ACC_PER_LAYER)      // 56640 doubles = 453120 B
#define HB_OFF_B      ((size_t)ACC_TOTAL * 8)

// ---------------------------------------------------------------------------
// Stats finalize, parallel + coalesced:
//  phase 1 (236 threads): each loads ONE contiguous 128B chunk (8 slots) of
//          acc_prev -> partial (s1,s2) into LDS.   [fully coalesced 30KB]
//  phase 2 (59 threads): combine 4 partials, finalize mu/var -> scsh float2.
// ---------------------------------------------------------------------------
__device__ __forceinline__ void scsh_partial(const double* __restrict__ acc_prev,
                                             double2* part, int tid)
{
  if (tid < 4 * F) {
    const int j = tid >> 2, c = tid & 3;
    const double* p = acc_prev + (size_t)j * (NSLC * 2) + c * 16;
    double s1 = 0.0, s2 = 0.0;
    #pragma unroll
    for (int i = 0; i < 8; ++i) { s1 += p[2 * i]; s2 += p[2 * i + 1]; }
    part[tid] = make_double2(s1, s2);
  }
}

__device__ __forceinline__ void scsh_finalize(const double2* part,
                                              const float* __restrict__ g,
                                              const float* __restrict__ bt,
                                              float2* scsh, int tid)
{
  if (tid < F) {
    double2 p0 = part[4 * tid], p1 = part[4 * tid + 1];
    double2 p2 = part[4 * tid + 2], p3 = part[4 * tid + 3];
    double s1 = p0.x + p1.x + p2.x + p3.x;
    double s2 = p0.y + p1.y + p2.y + p3.y;
    const double inv = 1.0 / (double)B;
    double mu   = s1 * inv;
    double var  = fma(s2, inv, -mu * mu);        // biased variance, fp64
    double rstd = 1.0 / sqrt(var + 1e-5);
    double sc   = rstd * (double)g[tid];
    scsh[tid] = make_float2((float)sc, (float)fma(-mu, sc, (double)bt[tid]));
  }
}

// ---------------------------------------------------------------------------
// One Linear+ReLU layer. Block = 64 rows (row = lane); wave q owns features
// q*15..q*15+14 (wave 3: 14 real + 1 clamped dup). Pipeline:
//   [stage raw h -> LDS  ||  coalesced acc partials] -> barrier
//   -> finalize scsh -> barrier
//   -> h into REGISTERS (normalize-on-load, asm-pinned: no LDS rematerialize)
//   -> j-outer/k-inner pure v_fmac (W via s_load, SGPR operand)
//   -> coalesced y stores -> 15-feature butterfly stats -> sliced f64 atomics.
// ---------------------------------------------------------------------------
template<int K, bool FIRST>
__global__ void __launch_bounds__(NTHR, 5)
layer_kernel(const float* __restrict__ in, const float* __restrict__ W,
             const float* __restrict__ bvec,
             const double* __restrict__ acc_prev,    // prev stats (unless FIRST)
             const float* __restrict__ g_prev, const float* __restrict__ bt_prev,
             float* __restrict__ hout, double* acc)
{
  __shared__ float   hbuf[FIRST ? ((K0 + 1) * 64) : (K * 64)];
  __shared__ float2  scsh[64];
  __shared__ double2 part[240];

  const int tid   = threadIdx.x;
  const int lane  = tid & 63;
  const int qu    = __builtin_amdgcn_readfirstlane(tid >> 6);
  const int rowbase = blockIdx.x * RPB;
  const int slice   = blockIdx.x & (NSLC - 1);

  // ---- phase A: acc partials (coalesced, 236 threads) ----
  if (!FIRST) scsh_partial(acc_prev, part, tid);

  // ---- phase B: stage raw input rows (overlaps A; no normalize here) ----
  if (FIRST) {
    const float* xblk = in + (size_t)rowbase * K;
    #pragma unroll 4
    for (int i = tid; i < RPB * K; i += NTHR) {
      int r = i / K, k = i - r * K;
      hbuf[r * (K + 1) + k] = xblk[i];               // [r][K+1], 2-way ok
    }
  } else {
    #pragma unroll 4
    for (int i = tid; i < K * 64; i += NTHR) {
      int k = i >> 6, r = i & 63;
      hbuf[i] = in[(size_t)k * B + rowbase + r];     // [k][64], coalesced in
    }
  }
  __syncthreads();

  if (!FIRST) {
    scsh_finalize(part, g_prev, bt_prev, scsh, tid);
    __syncthreads();
  }

  // ---- h -> REGISTERS (normalized), pinned against rematerialization ----
  float h[K];
  #pragma unroll
  for (int k = 0; k < K; ++k) {
    float v;
    if (FIRST) {
      v = hbuf[lane * (K + 1) + k];
    } else {
      float2 s = scsh[k];                            // LDS broadcast
      v = fmaf(hbuf[k * 64 + lane], s.x, s.y);
    }
    asm volatile("" : "+v"(v));                      // pin in VGPR
    h[k] = v;
  }

  // ---- j-outer / k-inner: W contiguous -> s_load, SGPR-operand FMAs ----
  const int fbase = qu * 15;
  float y[15];
  #pragma unroll
  for (int j = 0; j < 15; ++j) {
    int wrow = fbase + j;
    wrow = wrow > F - 1 ? F - 1 : wrow;              // scalar clamp (wave 3)
    const float* wp = W + (size_t)wrow * K;
    float a = bvec[wrow];
    #pragma unroll
    for (int k = 0; k < K; ++k) a = fmaf(h[k], wp[k], a);
    y[j] = fmaxf(a, 0.f);
  }

  // ---- coalesced stores to the pong buffer ----
  float* op = hout + rowbase + lane;
  #pragma unroll
  for (int j = 0; j < 15; ++j) {
    int f = fbase + j;
    if (f < F) op[(size_t)f * B] = y[j];             // uniform guard
  }

  // ---- stats: 15 butterflies with cross-feature ILP ----
  float ms = 0.f, mss = 0.f;
  #pragma unroll
  for (int j = 0; j < 15; ++j) {
    if (fbase + j < F) {                             // uniform guard
      float s = y[j], ss = y[j] * y[j];
      #pragma unroll
      for (int m = 1; m < 64; m <<= 1) {
        s  += __shfl_xor(s,  m, 64);
        ss += __shfl_xor(ss, m, 64);
      }
      if (lane == j) { ms = s; mss = ss; }
    }
  }
  if (lane < 15 && fbase + lane < F) {
    double* slot = acc + ((size_t)(fbase + lane) * NSLC + slice) * 2;
    atomicAdd(slot,     (double)ms);                 // hw f64 atomic
    atomicAdd(slot + 1, (double)mss);
  }
}

// ---------------------------------------------------------------------------
// Final BN: hT -> row-major out via LDS transpose tile (64 rows/block).
// ---------------------------------------------------------------------------
__global__ void __launch_bounds__(NTHR, 5)
final_tr_kernel(const float* __restrict__ hT, const double* __restrict__ acc_last,
                const float* __restrict__ g, const float* __restrict__ bt,
                float* __restrict__ out)
{
  __shared__ float2  scsh[64];
  __shared__ double2 part[240];
  __shared__ float   ybuf[RPB * 61];
  const int tid = threadIdx.x;

  scsh_partial(acc_last, part, tid);
  __syncthreads();
  scsh_finalize(part, g, bt, scsh, tid);
  __syncthreads();

  const int rowbase = blockIdx.x * RPB;
  for (int i = tid; i < F * RPB; i += NTHR) {
    int j = i >> 6, r = i & 63;
    float2 s = scsh[j];
    ybuf[r * 61 + j] = fmaf(hT[(size_t)j * B + rowbase + r], s.x, s.y);
  }
  __syncthreads();

  float* oblk = out + (size_t)rowbase * F;
  for (int i = tid; i < RPB * F; i += NTHR) {
    int r = i / F, j = i - r * F;
    oblk[i] = ybuf[r * 61 + j];
  }
}

// ---------------------------------------------------------------------------
extern "C" void kernel_launch(void* const* d_in, const int* in_sizes, int n_in,
                              void* d_out, int out_size, void* d_ws, size_t ws_size,
                              hipStream_t stream)
{
  const float* x   = (const float*)d_in[0];
  const float* W0  = (const float*)d_in[1];
  const float* b0  = (const float*)d_in[2];
  const float* g0  = (const float*)d_in[3];
  const float* bt0 = (const float*)d_in[4];
  const float* Ws  = (const float*)d_in[5];
  const float* bs  = (const float*)d_in[6];
  const float* gs  = (const float*)d_in[7];
  const float* bts = (const float*)d_in[8];
  float* out = (float*)d_out;

  double* acc = (double*)d_ws;                       // [NB][F][NSLC][2]
  float*  hB  = (float*)((char*)d_ws + HB_OFF_B);    // [F][B] in workspace
  float*  hA  = out;                                 // [F][B] alias of d_out

  // zero the atomic accumulators every call (deterministic, capture-safe)
  hipMemsetAsync(d_ws, 0, (size_t)ACC_TOTAL * sizeof(double), stream);

  // layer 0: x[B,29] -> hB
  layer_kernel<K0, true><<<NBLK, NTHR, 0, stream>>>(
      x, W0, b0, nullptr, nullptr, nullptr, hB, acc);

  // layers 1..14: ping-pong hB <-> hA (d_out), normalize-prev-on-read
  for (int b = 1; b < NB; ++b) {
    const float* gp  = (b == 1) ? g0  : gs  + (size_t)(b - 2) * F;
    const float* btp = (b == 1) ? bt0 : bts + (size_t)(b - 2) * F;
    const float* src = (b & 1) ? hB : hA;
    float*       dst = (b & 1) ? hA : hB;
    layer_kernel<F, false><<<NBLK, NTHR, 0, stream>>>(
        src, Ws + (size_t)(b - 1) * F * F, bs + (size_t)(b - 1) * F,
        acc + (size_t)(b - 1) * ACC_PER_LAYER, gp, btp,
        dst, acc + (size_t)b * ACC_PER_LAYER);
  }

  // layer 14 wrote hB (14 even) -> final BN into row-major d_out
  final_tr_kernel<<<NBLK, NTHR, 0, stream>>>(
      hB, acc + (size_t)(NB - 1) * ACC_PER_LAYER,
      gs + (size_t)(NB - 2) * F, bts + (size_t)(NB - 2) * F, out);
}

// Round 12
// 632.631 us; speedup vs baseline: 6.2701x; 6.2701x over previous
//
#include <hip/hip_runtime.h>

#define NTHR  256
#define F     59
#define K0    29
#define NB    15
#define B     131072
#define RPB   64                 // rows per block (= wavefront size)
#define NBLK  (B / RPB)          // 2048 blocks
#define NSLC  32                 // f64 atomic slices; 16B slot per (feature,slice)
#define FPW   16                 // features per wave (16/16/16/11 real)

// d_ws layout: acc[NB][F][NSLC][2] dbl | Wt[(29+14*59)][64] f32 | hB[F][B] f32
#define ACC_PER_LAYER (F * NSLC * 2)            // 3776 doubles / layer
#define ACC_TOTAL     (NB * ACC_PER_LAYER)      // 56640 doubles = 453120 B
#define WT_OFF_B      ((size_t)ACC_TOTAL * 8)
#define WT_FLOATS     ((K0 + 14 * F) * 64)      // 54720 floats
#define HB_OFF_B      (WT_OFF_B + (size_t)WT_FLOATS * 4)

// ---------------------------------------------------------------------------
// Per-layer W transpose: Wt[k][j] = W[j][k], j padded to 64 with zeros.
// 15 blocks, ~15KB each — runs once per call, ~4 us.
// ---------------------------------------------------------------------------
__global__ void transpose_w(const float* __restrict__ W0,
                            const float* __restrict__ Ws,
                            float* __restrict__ Wt)
{
  const int b = blockIdx.x;
  const float* W = (b == 0) ? W0 : Ws + (size_t)(b - 1) * F * F;
  const int K   = (b == 0) ? K0 : F;
  float* dst = (b == 0) ? Wt : Wt + (size_t)K0 * 64 + (size_t)(b - 1) * F * 64;
  for (int i = threadIdx.x; i < K * 64; i += blockDim.x) {
    int k = i >> 6, j = i & 63;
    dst[i] = (j < F) ? W[j * K + k] : 0.f;
  }
}

// ---------------------------------------------------------------------------
// Stats finalize, parallel + coalesced (proven in R11):
//  phase 1 (236 threads): one contiguous 128B chunk (8 slots) each -> part.
//  phase 2 (59 threads): combine 4 partials -> mu/var -> scsh float2.
// ---------------------------------------------------------------------------
__device__ __forceinline__ void scsh_partial(const double* __restrict__ acc_prev,
                                             double2* part, int tid)
{
  if (tid < 4 * F) {
    const int j = tid >> 2, c = tid & 3;
    const double* p = acc_prev + (size_t)j * (NSLC * 2) + c * 16;
    double s1 = 0.0, s2 = 0.0;
    #pragma unroll
    for (int i = 0; i < 8; ++i) { s1 += p[2 * i]; s2 += p[2 * i + 1]; }
    part[tid] = make_double2(s1, s2);
  }
}

__device__ __forceinline__ void scsh_finalize(const double2* part,
                                              const float* __restrict__ g,
                                              const float* __restrict__ bt,
                                              float2* scsh, int tid)
{
  if (tid < F) {
    double2 p0 = part[4 * tid], p1 = part[4 * tid + 1];
    double2 p2 = part[4 * tid + 2], p3 = part[4 * tid + 3];
    double s1 = p0.x + p1.x + p2.x + p3.x;
    double s2 = p0.y + p1.y + p2.y + p3.y;
    const double inv = 1.0 / (double)B;
    double mu   = s1 * inv;
    double var  = fma(s2, inv, -mu * mu);        // biased variance, fp64
    double rstd = 1.0 / sqrt(var + 1e-5);
    double sc   = rstd * (double)g[tid];
    scsh[tid] = make_float2((float)sc, (float)fma(-mu, sc, (double)bt[tid]));
  }
}

// ---------------------------------------------------------------------------
// One Linear+ReLU layer. Block = 64 rows (row = lane); wave q owns features
// 16q..16q+15 (f < 59 guarded, wave-uniform). k-OUTER loop:
//   hk   = ds_read hbuf[k][lane]  (+ inline normalize via scsh[k] broadcast)
//   Wt[k][16q..16q+15]            -> one s_load_dwordx16 (contiguous, uniform)
//   16 x v_fmac (scalar W operand) into acc_[16]     => ~40 VGPR, no arrays
// Then ReLU -> coalesced stores -> 16-feature butterfly stats -> f64 atomics.
// ---------------------------------------------------------------------------
template<int K, bool FIRST>
__global__ void __launch_bounds__(NTHR, 8)
layer_kernel(const float* __restrict__ in, const float* __restrict__ Wt,
             const float* __restrict__ bvec,
             const double* __restrict__ acc_prev,    // prev stats (unless FIRST)
             const float* __restrict__ g_prev, const float* __restrict__ bt_prev,
             float* __restrict__ hout, double* acc)
{
  __shared__ float   hbuf[FIRST ? (RPB * 33) : (K * 64)];
  __shared__ float2  scsh[64];
  __shared__ double2 part[240];

  const int tid   = threadIdx.x;
  const int lane  = tid & 63;
  const int qu    = __builtin_amdgcn_readfirstlane(tid >> 6);
  const int rowbase = blockIdx.x * RPB;
  const int slice   = blockIdx.x & (NSLC - 1);

  // ---- phase A: acc partials (coalesced) overlapped with raw staging ----
  if (!FIRST) scsh_partial(acc_prev, part, tid);

  if (FIRST) {
    const float* xblk = in + (size_t)rowbase * K;    // row-major x
    for (int i = tid; i < RPB * K; i += NTHR) {
      int r = i / K, k = i - r * K;
      hbuf[r * 33 + k] = xblk[i];                    // [r][33]: 2-way ok
    }
  } else {
    // hT is [F][B]: float4 over rows, coalesced 16B/lane
    for (int i = tid; i < K * 16; i += NTHR) {
      int k = i >> 4, r4 = i & 15;
      float4 v = *(const float4*)(in + (size_t)k * B + rowbase + r4 * 4);
      *(float4*)&hbuf[k * 64 + r4 * 4] = v;          // [k][64]: raw (unnormalized)
    }
  }
  __syncthreads();

  if (!FIRST) {
    scsh_finalize(part, g_prev, bt_prev, scsh, tid);
    __syncthreads();
  }

  // ---- k-outer matmul ----
  const int fbase = qu * FPW;
  float a0,a1,a2,a3,a4,a5,a6,a7,a8,a9,a10,a11,a12,a13,a14,a15;
  {
    #define BV(j) bvec[(fbase + j) > (F - 1) ? (F - 1) : (fbase + j)]
    a0=BV(0); a1=BV(1); a2=BV(2); a3=BV(3); a4=BV(4); a5=BV(5); a6=BV(6); a7=BV(7);
    a8=BV(8); a9=BV(9); a10=BV(10); a11=BV(11); a12=BV(12); a13=BV(13); a14=BV(14); a15=BV(15);
    #undef BV
  }
  #pragma unroll 2
  for (int k = 0; k < K; ++k) {
    float hk;
    if (FIRST) {
      hk = hbuf[lane * 33 + k];
    } else {
      float2 s = scsh[k];                            // ds_read_b64 broadcast
      hk = fmaf(hbuf[k * 64 + lane], s.x, s.y);      // normalize inline
    }
    const float* wk = Wt + k * 64 + fbase;           // uniform -> s_load x16
    a0  = fmaf(hk, wk[0],  a0);  a1  = fmaf(hk, wk[1],  a1);
    a2  = fmaf(hk, wk[2],  a2);  a3  = fmaf(hk, wk[3],  a3);
    a4  = fmaf(hk, wk[4],  a4);  a5  = fmaf(hk, wk[5],  a5);
    a6  = fmaf(hk, wk[6],  a6);  a7  = fmaf(hk, wk[7],  a7);
    a8  = fmaf(hk, wk[8],  a8);  a9  = fmaf(hk, wk[9],  a9);
    a10 = fmaf(hk, wk[10], a10); a11 = fmaf(hk, wk[11], a11);
    a12 = fmaf(hk, wk[12], a12); a13 = fmaf(hk, wk[13], a13);
    a14 = fmaf(hk, wk[14], a14); a15 = fmaf(hk, wk[15], a15);
  }

  // ---- ReLU + coalesced stores + butterfly stats + sliced atomics ----
  float ms = 0.f, mss = 0.f;
  float* op = hout + rowbase + lane;
  #define FIN(j, aj)                                                        \
  {                                                                         \
    if (fbase + j < F) {                       /* wave-uniform guard */     \
      float y = fmaxf(aj, 0.f);                                             \
      op[(size_t)(fbase + j) * B] = y;                                      \
      float s = y, ss = y * y;                                              \
      _Pragma("unroll")                                                     \
      for (int m = 1; m < 64; m <<= 1) {                                    \
        s  += __shfl_xor(s,  m, 64);                                        \
        ss += __shfl_xor(ss, m, 64);                                        \
      }                                                                     \
      if (lane == j) { ms = s; mss = ss; }                                  \
    }                                                                       \
  }
  FIN(0,a0)  FIN(1,a1)  FIN(2,a2)  FIN(3,a3)  FIN(4,a4)  FIN(5,a5)
  FIN(6,a6)  FIN(7,a7)  FIN(8,a8)  FIN(9,a9)  FIN(10,a10) FIN(11,a11)
  FIN(12,a12) FIN(13,a13) FIN(14,a14) FIN(15,a15)
  #undef FIN

  if (lane < FPW && fbase + lane < F) {
    double* slot = acc + ((size_t)(fbase + lane) * NSLC + slice) * 2;
    atomicAdd(slot,     (double)ms);                 // hw f64 atomic
    atomicAdd(slot + 1, (double)mss);
  }
}

// ---------------------------------------------------------------------------
// Final BN: hT -> row-major out via LDS transpose tile (64 rows/block).
// ---------------------------------------------------------------------------
__global__ void __launch_bounds__(NTHR, 8)
final_tr_kernel(const float* __restrict__ hT, const double* __restrict__ acc_last,
                const float* __restrict__ g, const float* __restrict__ bt,
                float* __restrict__ out)
{
  __shared__ float2  scsh[64];
  __shared__ double2 part[240];
  __shared__ float   ybuf[RPB * 61];
  const int tid = threadIdx.x;

  scsh_partial(acc_last, part, tid);
  __syncthreads();
  scsh_finalize(part, g, bt, scsh, tid);
  __syncthreads();

  const int rowbase = blockIdx.x * RPB;
  for (int i = tid; i < F * RPB; i += NTHR) {
    int j = i >> 6, r = i & 63;
    float2 s = scsh[j];
    ybuf[r * 61 + j] = fmaf(hT[(size_t)j * B + rowbase + r], s.x, s.y);
  }
  __syncthreads();

  float* oblk = out + (size_t)rowbase * F;
  for (int i = tid; i < RPB * F; i += NTHR) {
    int r = i / F, j = i - r * F;
    oblk[i] = ybuf[r * 61 + j];
  }
}

// ---------------------------------------------------------------------------
extern "C" void kernel_launch(void* const* d_in, const int* in_sizes, int n_in,
                              void* d_out, int out_size, void* d_ws, size_t ws_size,
                              hipStream_t stream)
{
  const float* x   = (const float*)d_in[0];
  const float* W0  = (const float*)d_in[1];
  const float* b0  = (const float*)d_in[2];
  const float* g0  = (const float*)d_in[3];
  const float* bt0 = (const float*)d_in[4];
  const float* Ws  = (const float*)d_in[5];
  const float* bs  = (const float*)d_in[6];
  const float* gs  = (const float*)d_in[7];
  const float* bts = (const float*)d_in[8];
  float* out = (float*)d_out;

  double* acc = (double*)d_ws;                       // [NB][F][NSLC][2]
  float*  Wt  = (float*)((char*)d_ws + WT_OFF_B);    // [29+14*59][64]
  float*  hB  = (float*)((char*)d_ws + HB_OFF_B);    // [F][B] in workspace
  float*  hA  = out;                                 // [F][B] alias of d_out

  // zero the atomic accumulators every call (deterministic, capture-safe)
  hipMemsetAsync(d_ws, 0, (size_t)ACC_TOTAL * sizeof(double), stream);

  // transpose all 15 weight matrices (zero-padded to j<64)
  transpose_w<<<NB, NTHR, 0, stream>>>(W0, Ws, Wt);

  // layer 0: x[B,29] -> hB
  layer_kernel<K0, true><<<NBLK, NTHR, 0, stream>>>(
      x, Wt, b0, nullptr, nullptr, nullptr, hB, acc);

  // layers 1..14: ping-pong hB <-> hA (d_out), normalize-prev-on-read
  for (int b = 1; b < NB; ++b) {
    const float* gp  = (b == 1) ? g0  : gs  + (size_t)(b - 2) * F;
    const float* btp = (b == 1) ? bt0 : bts + (size_t)(b - 2) * F;
    const float* src = (b & 1) ? hB : hA;
    float*       dst = (b & 1) ? hA : hB;
    const float* Wtb = Wt + (size_t)K0 * 64 + (size_t)(b - 1) * F * 64;
    layer_kernel<F, false><<<NBLK, NTHR, 0, stream>>>(
        src, Wtb, bs + (size_t)(b - 1) * F,
        acc + (size_t)(b - 1) * ACC_PER_LAYER, gp, btp,
        dst, acc + (size_t)b * ACC_PER_LAYER);
  }

  // layer 14 wrote hB (b=14 even) -> final BN into row-major d_out
  final_tr_kernel<<<NBLK, NTHR, 0, stream>>>(
      hB, acc + (size_t)(NB - 1) * ACC_PER_LAYER,
      gs + (size_t)(NB - 2) * F, bts + (size_t)(NB - 2) * F, out);
}

// Round 13
// 580.423 us; speedup vs baseline: 6.8341x; 1.0899x over previous
//
#include <hip/hip_runtime.h>

#define NTHR  256
#define F     59
#define K0    29
#define NB    15
#define B     131072
#define RPB   64                 // rows per block (= wavefront size)
#define NBLK  (B / RPB)          // 2048 blocks
#define NSLC  32                 // f64 atomic slices; 16B slot per (feature,slice)
#define FPW   16                 // features per wave (16/16/16/11 real)

// d_ws layout: acc[NB][F][NSLC][2] dbl | Wt[(29+14*59)][64] f32 | hB[F][B] f32
#define ACC_PER_LAYER (F * NSLC * 2)            // 3776 doubles / layer
#define ACC_TOTAL     (NB * ACC_PER_LAYER)      // 56640 doubles = 453120 B
#define WT_OFF_B      ((size_t)ACC_TOTAL * 8)
#define WT_FLOATS     ((K0 + 14 * F) * 64)      // 54720 floats
#define HB_OFF_B      (WT_OFF_B + (size_t)WT_FLOATS * 4)

// ---------------------------------------------------------------------------
// Per-layer W transpose: Wt[k][j] = W[j][k], j padded to 64 with zeros.
// ---------------------------------------------------------------------------
__global__ void transpose_w(const float* __restrict__ W0,
                            const float* __restrict__ Ws,
                            float* __restrict__ Wt)
{
  const int b = blockIdx.x;
  const float* W = (b == 0) ? W0 : Ws + (size_t)(b - 1) * F * F;
  const int K   = (b == 0) ? K0 : F;
  float* dst = (b == 0) ? Wt : Wt + (size_t)K0 * 64 + (size_t)(b - 1) * F * 64;
  for (int i = threadIdx.x; i < K * 64; i += blockDim.x) {
    int k = i >> 6, j = i & 63;
    dst[i] = (j < F) ? W[j * K + k] : 0.f;
  }
}

// ---------------------------------------------------------------------------
// scsh by wave 0 only: lane j (<59) reads feature j's 32 (sum,sumsq) slots
// (contiguous 512B) and finalizes fp64 mu/var -> scsh[j] (float2).
// ---------------------------------------------------------------------------
__device__ __forceinline__ void scsh_wave0(const double* __restrict__ acc_prev,
                                           const float* __restrict__ g,
                                           const float* __restrict__ bt,
                                           float2* scsh, int lane)
{
  if (lane < F) {
    const double* p = acc_prev + (size_t)lane * (NSLC * 2);
    double s1 = 0.0, s2 = 0.0;
    #pragma unroll
    for (int s = 0; s < NSLC; ++s) { s1 += p[2 * s]; s2 += p[2 * s + 1]; }
    const double inv = 1.0 / (double)B;
    double mu   = s1 * inv;
    double var  = fma(s2, inv, -mu * mu);        // biased variance, fp64
    double rstd = 1.0 / sqrt(var + 1e-5);
    double sc   = rstd * (double)g[lane];
    scsh[lane] = make_float2((float)sc, (float)fma(-mu, sc, (double)bt[lane]));
  }
}

// ---------------------------------------------------------------------------
// One Linear+ReLU layer. Block = 64 rows (row = lane); wave q owns features
// 16q..16q+15 (f < 59 guarded, wave-uniform). Prologue (single barrier):
//   wave 0: compute scsh from acc_prev  ||  waves 1-3: stage raw h (float4).
// k-OUTER loop (unroll 4): hk = ds_read + inline normalize; Wt[k][fbase..]
// via s_load_dwordx16 feeding v_fmac's scalar operand; 16 accumulators only.
// Epilogue: ReLU -> coalesced stores -> 16-feature butterfly -> f64 atomics.
// ---------------------------------------------------------------------------
template<int K, bool FIRST>
__global__ void __launch_bounds__(NTHR, 8)
layer_kernel(const float* __restrict__ in, const float* __restrict__ Wt,
             const float* __restrict__ bvec,
             const double* __restrict__ acc_prev,    // prev stats (unless FIRST)
             const float* __restrict__ g_prev, const float* __restrict__ bt_prev,
             float* __restrict__ hout, double* acc)
{
  __shared__ float  hbuf[FIRST ? (RPB * 33) : (K * 64)];   // 8448 / 15104 B
  __shared__ float2 scsh[64];                              //   512 B

  const int tid   = threadIdx.x;
  const int lane  = tid & 63;
  const int qu    = __builtin_amdgcn_readfirstlane(tid >> 6);
  const int rowbase = blockIdx.x * RPB;
  const int slice   = blockIdx.x & (NSLC - 1);

  // ---- prologue: scsh (wave 0) overlapped with raw staging (waves 1-3) ----
  if (FIRST) {
    const float* xblk = in + (size_t)rowbase * K;    // row-major x
    for (int i = tid; i < RPB * K; i += NTHR) {
      int r = i / K, k = i - r * K;
      hbuf[r * 33 + k] = xblk[i];                    // [r][33]: 2-way ok
    }
  } else {
    if (qu == 0) {
      scsh_wave0(acc_prev, g_prev, bt_prev, scsh, lane);
    } else {
      // hT is [F][B]: float4 over rows, coalesced 16B/lane, 192 threads
      for (int i = tid - 64; i < K * 16; i += (NTHR - 64)) {
        int k = i >> 4, r4 = i & 15;
        float4 v = *(const float4*)(in + (size_t)k * B + rowbase + r4 * 4);
        *(float4*)&hbuf[k * 64 + r4 * 4] = v;        // [k][64], raw
      }
    }
  }
  __syncthreads();

  // ---- k-outer matmul ----
  const int fbase = qu * FPW;
  float a0,a1,a2,a3,a4,a5,a6,a7,a8,a9,a10,a11,a12,a13,a14,a15;
  {
    #define BV(j) bvec[(fbase + j) > (F - 1) ? (F - 1) : (fbase + j)]
    a0=BV(0); a1=BV(1); a2=BV(2); a3=BV(3); a4=BV(4); a5=BV(5); a6=BV(6); a7=BV(7);
    a8=BV(8); a9=BV(9); a10=BV(10); a11=BV(11); a12=BV(12); a13=BV(13); a14=BV(14); a15=BV(15);
    #undef BV
  }
  #pragma unroll 4
  for (int k = 0; k < K; ++k) {
    float hk;
    if (FIRST) {
      hk = hbuf[lane * 33 + k];
    } else {
      float2 s = scsh[k];                            // ds_read_b64 broadcast
      hk = fmaf(hbuf[k * 64 + lane], s.x, s.y);      // normalize inline
    }
    const float* wk = Wt + k * 64 + fbase;           // uniform -> s_load x16
    a0  = fmaf(hk, wk[0],  a0);  a1  = fmaf(hk, wk[1],  a1);
    a2  = fmaf(hk, wk[2],  a2);  a3  = fmaf(hk, wk[3],  a3);
    a4  = fmaf(hk, wk[4],  a4);  a5  = fmaf(hk, wk[5],  a5);
    a6  = fmaf(hk, wk[6],  a6);  a7  = fmaf(hk, wk[7],  a7);
    a8  = fmaf(hk, wk[8],  a8);  a9  = fmaf(hk, wk[9],  a9);
    a10 = fmaf(hk, wk[10], a10); a11 = fmaf(hk, wk[11], a11);
    a12 = fmaf(hk, wk[12], a12); a13 = fmaf(hk, wk[13], a13);
    a14 = fmaf(hk, wk[14], a14); a15 = fmaf(hk, wk[15], a15);
  }

  // ---- ReLU + coalesced stores + butterfly stats + sliced atomics ----
  float ms = 0.f, mss = 0.f;
  float* op = hout + rowbase + lane;
  #define FIN(j, aj)                                                        \
  {                                                                         \
    if (fbase + j < F) {                       /* wave-uniform guard */     \
      float y = fmaxf(aj, 0.f);                                             \
      op[(size_t)(fbase + j) * B] = y;                                      \
      float s = y, ss = y * y;                                              \
      _Pragma("unroll")                                                     \
      for (int m = 1; m < 64; m <<= 1) {                                    \
        s  += __shfl_xor(s,  m, 64);                                        \
        ss += __shfl_xor(ss, m, 64);                                        \
      }                                                                     \
      if (lane == j) { ms = s; mss = ss; }                                  \
    }                                                                       \
  }
  FIN(0,a0)  FIN(1,a1)  FIN(2,a2)  FIN(3,a3)  FIN(4,a4)  FIN(5,a5)
  FIN(6,a6)  FIN(7,a7)  FIN(8,a8)  FIN(9,a9)  FIN(10,a10) FIN(11,a11)
  FIN(12,a12) FIN(13,a13) FIN(14,a14) FIN(15,a15)
  #undef FIN

  if (lane < FPW && fbase + lane < F) {
    double* slot = acc + ((size_t)(fbase + lane) * NSLC + slice) * 2;
    atomicAdd(slot,     (double)ms);                 // hw f64 atomic
    atomicAdd(slot + 1, (double)mss);
  }
}

// ---------------------------------------------------------------------------
// Final BN: hT -> row-major out. Wave 0 scsh || waves 1-3 stage raw hT;
// barrier; all threads write out with normalize inline.
// ---------------------------------------------------------------------------
__global__ void __launch_bounds__(NTHR, 8)
final_tr_kernel(const float* __restrict__ hT, const double* __restrict__ acc_last,
                const float* __restrict__ g, const float* __restrict__ bt,
                float* __restrict__ out)
{
  __shared__ float2 scsh[64];
  __shared__ float  ybuf[F * 64];                    // [j][64] raw
  const int tid  = threadIdx.x;
  const int lane = tid & 63;
  const int qu   = __builtin_amdgcn_readfirstlane(tid >> 6);
  const int rowbase = blockIdx.x * RPB;

  if (qu == 0) {
    scsh_wave0(acc_last, g, bt, scsh, lane);
  } else {
    for (int i = tid - 64; i < F * 16; i += (NTHR - 64)) {
      int j = i >> 4, r4 = i & 15;
      float4 v = *(const float4*)(hT + (size_t)j * B + rowbase + r4 * 4);
      *(float4*)&ybuf[j * 64 + r4 * 4] = v;
    }
  }
  __syncthreads();

  float* oblk = out + (size_t)rowbase * F;
  for (int i = tid; i < RPB * F; i += NTHR) {
    int r = i / F, j = i - r * F;
    float2 s = scsh[j];
    oblk[i] = fmaf(ybuf[j * 64 + r], s.x, s.y);
  }
}

// ---------------------------------------------------------------------------
extern "C" void kernel_launch(void* const* d_in, const int* in_sizes, int n_in,
                              void* d_out, int out_size, void* d_ws, size_t ws_size,
                              hipStream_t stream)
{
  const float* x   = (const float*)d_in[0];
  const float* W0  = (const float*)d_in[1];
  const float* b0  = (const float*)d_in[2];
  const float* g0  = (const float*)d_in[3];
  const float* bt0 = (const float*)d_in[4];
  const float* Ws  = (const float*)d_in[5];
  const float* bs  = (const float*)d_in[6];
  const float* gs  = (const float*)d_in[7];
  const float* bts = (const float*)d_in[8];
  float* out = (float*)d_out;

  double* acc = (double*)d_ws;                       // [NB][F][NSLC][2]
  float*  Wt  = (float*)((char*)d_ws + WT_OFF_B);    // [29+14*59][64]
  float*  hB  = (float*)((char*)d_ws + HB_OFF_B);    // [F][B] in workspace
  float*  hA  = out;                                 // [F][B] alias of d_out

  // zero the atomic accumulators every call (deterministic, capture-safe)
  hipMemsetAsync(d_ws, 0, (size_t)ACC_TOTAL * sizeof(double), stream);

  // transpose all 15 weight matrices (zero-padded to j<64)
  transpose_w<<<NB, NTHR, 0, stream>>>(W0, Ws, Wt);

  // layer 0: x[B,29] -> hB
  layer_kernel<K0, true><<<NBLK, NTHR, 0, stream>>>(
      x, Wt, b0, nullptr, nullptr, nullptr, hB, acc);

  // layers 1..14: ping-pong hB <-> hA (d_out), normalize-prev-on-read
  for (int b = 1; b < NB; ++b) {
    const float* gp  = (b == 1) ? g0  : gs  + (size_t)(b - 2) * F;
    const float* btp = (b == 1) ? bt0 : bts + (size_t)(b - 2) * F;
    const float* src = (b & 1) ? hB : hA;
    float*       dst = (b & 1) ? hA : hB;
    const float* Wtb = Wt + (size_t)K0 * 64 + (size_t)(b - 1) * F * 64;
    layer_kernel<F, false><<<NBLK, NTHR, 0, stream>>>(
        src, Wtb, bs + (size_t)(b - 1) * F,
        acc + (size_t)(b - 1) * ACC_PER_LAYER, gp, btp,
        dst, acc + (size_t)b * ACC_PER_LAYER);
  }

  // layer 14 wrote hB (b=14 even) -> final BN into row-major d_out
  final_tr_kernel<<<NBLK, NTHR, 0, stream>>>(
      hB, acc + (size_t)(NB - 1) * ACC_PER_LAYER,
      gs + (size_t)(NB - 2) * F, bts + (size_t)(NB - 2) * F, out);
}

// Round 14
// 464.360 us; speedup vs baseline: 8.5422x; 1.2499x over previous
//
#include <hip/hip_runtime.h>

#define NTHR  256
#define F     59
#define K0    29
#define NB    15
#define B     131072
#define RPB   64                 // rows per block (= wavefront size)
#define NBLK  (B / RPB)          // 2048 blocks
#define NSLC  32                 // f64 atomic slices; 16B slot per (feature,slice)
#define FPW   16                 // features per wave (16/16/16/11 real)
#define HSTR  68                 // hbuf k-row stride (4(k+r) banks: ~4-way writes)
#define YSTR  68                 // ytile feature stride (16B-aligned b128 reads)

// d_ws layout: acc[NB][F][NSLC][2] dbl | Wt[(29+14*59)][64] f32 | hB[F][B] f32
#define ACC_PER_LAYER (F * NSLC * 2)            // 3776 doubles / layer
#define ACC_TOTAL     (NB * ACC_PER_LAYER)      // 56640 doubles = 453120 B
#define WT_OFF_B      ((size_t)ACC_TOTAL * 8)
#define WT_FLOATS     ((K0 + 14 * F) * 64)      // 54720 floats
#define HB_OFF_B      (WT_OFF_B + (size_t)WT_FLOATS * 4)

// ---------------------------------------------------------------------------
// Per-layer W transpose: Wt[k][j] = W[j][k], j padded to 64 with zeros.
// ---------------------------------------------------------------------------
__global__ void transpose_w(const float* __restrict__ W0,
                            const float* __restrict__ Ws,
                            float* __restrict__ Wt)
{
  const int b = blockIdx.x;
  const float* W = (b == 0) ? W0 : Ws + (size_t)(b - 1) * F * F;
  const int K   = (b == 0) ? K0 : F;
  float* dst = (b == 0) ? Wt : Wt + (size_t)K0 * 64 + (size_t)(b - 1) * F * 64;
  for (int i = threadIdx.x; i < K * 64; i += blockDim.x) {
    int k = i >> 6, j = i & 63;
    dst[i] = (j < F) ? W[j * K + k] : 0.f;
  }
}

// ---------------------------------------------------------------------------
// scsh by wave 0: lane j (<59) reads feature j's 32 (sum,sumsq) slots
// (contiguous 512B) and finalizes fp64 mu/var -> scsh[j] (float2).
// ---------------------------------------------------------------------------
__device__ __forceinline__ void scsh_wave0(const double* __restrict__ acc_prev,
                                           const float* __restrict__ g,
                                           const float* __restrict__ bt,
                                           float2* scsh, int lane)
{
  if (lane < F) {
    const double* p = acc_prev + (size_t)lane * (NSLC * 2);
    double s1 = 0.0, s2 = 0.0;
    #pragma unroll
    for (int s = 0; s < NSLC; ++s) { s1 += p[2 * s]; s2 += p[2 * s + 1]; }
    const double inv = 1.0 / (double)B;
    double mu   = s1 * inv;
    double var  = fma(s2, inv, -mu * mu);        // biased variance, fp64
    double rstd = 1.0 / sqrt(var + 1e-5);
    double sc   = rstd * (double)g[lane];
    scsh[lane] = make_float2((float)sc, (float)fma(-mu, sc, (double)bt[lane]));
  }
}

// ---------------------------------------------------------------------------
// One Linear+ReLU layer. Block = 64 rows (row = lane); wave q owns features
// 16q..16q+15 (f < 59 guarded, wave-uniform). Prologue (one barrier):
//   wave 0: scsh from acc_prev  ||  waves 1-3: stage raw h (float4, [k][68]).
// k-loop in PAIRS: one ds_read_b128 of scsh[k..k+1] + 2 hbuf b32 (ds_read2-
// mergeable) + 2 s_load_dwordx16 Wt rows + 32 v_fmac into 16 accumulators.
// Epilogue: ReLU -> coalesced stores -> barrier -> per-wave LDS y-tile
// (union with hbuf) -> 4x ds_read_b128 + 2 shfl_xor -> sliced f64 atomics.
// ---------------------------------------------------------------------------
template<int K, bool FIRST>
__global__ void __launch_bounds__(NTHR, 8)
layer_kernel(const float* __restrict__ in, const float* __restrict__ Wt,
             const float* __restrict__ bvec,
             const double* __restrict__ acc_prev,    // prev stats (unless FIRST)
             const float* __restrict__ g_prev, const float* __restrict__ bt_prev,
             float* __restrict__ hout, double* acc)
{
  // union: hbuf ([k][HSTR] or [r][33] for FIRST)  /  ytile (4 x [16][YSTR])
  __shared__ float lds[4 * FPW * YSTR];                    // 17408 B
  __shared__ __attribute__((aligned(16))) float2 scsh[64]; //   512 B

  const int tid   = threadIdx.x;
  const int lane  = tid & 63;
  const int qu    = __builtin_amdgcn_readfirstlane(tid >> 6);
  const int rowbase = blockIdx.x * RPB;
  const int slice   = blockIdx.x & (NSLC - 1);

  // ---- prologue: scsh (wave 0) overlapped with raw staging (waves 1-3) ----
  if (FIRST) {
    const float* xblk = in + (size_t)rowbase * K;    // row-major x
    for (int i = tid; i < RPB * K; i += NTHR) {
      int r = i / K, k = i - r * K;
      lds[r * 33 + k] = xblk[i];                     // [r][33]: 2-way ok
    }
  } else {
    if (qu == 0) {
      scsh_wave0(acc_prev, g_prev, bt_prev, scsh, lane);
    } else {
      // hT is [F][B]: float4 over rows, coalesced 16B/lane, 192 threads
      for (int i = tid - 64; i < K * 16; i += (NTHR - 64)) {
        int k = i >> 4, r4 = i & 15;
        float4 v = *(const float4*)(in + (size_t)k * B + rowbase + r4 * 4);
        *(float4*)&lds[k * HSTR + r4 * 4] = v;       // [k][68], ~4-way writes
      }
    }
  }
  __syncthreads();

  // ---- k-outer matmul, paired k ----
  const int fbase = qu * FPW;
  float a0,a1,a2,a3,a4,a5,a6,a7,a8,a9,a10,a11,a12,a13,a14,a15;
  {
    #define BV(j) bvec[(fbase + j) > (F - 1) ? (F - 1) : (fbase + j)]
    a0=BV(0); a1=BV(1); a2=BV(2); a3=BV(3); a4=BV(4); a5=BV(5); a6=BV(6); a7=BV(7);
    a8=BV(8); a9=BV(9); a10=BV(10); a11=BV(11); a12=BV(12); a13=BV(13); a14=BV(14); a15=BV(15);
    #undef BV
  }

  #define FMA16(hk, wk)                                                     \
    a0  = fmaf(hk, (wk)[0],  a0);  a1  = fmaf(hk, (wk)[1],  a1);            \
    a2  = fmaf(hk, (wk)[2],  a2);  a3  = fmaf(hk, (wk)[3],  a3);            \
    a4  = fmaf(hk, (wk)[4],  a4);  a5  = fmaf(hk, (wk)[5],  a5);            \
    a6  = fmaf(hk, (wk)[6],  a6);  a7  = fmaf(hk, (wk)[7],  a7);            \
    a8  = fmaf(hk, (wk)[8],  a8);  a9  = fmaf(hk, (wk)[9],  a9);            \
    a10 = fmaf(hk, (wk)[10], a10); a11 = fmaf(hk, (wk)[11], a11);           \
    a12 = fmaf(hk, (wk)[12], a12); a13 = fmaf(hk, (wk)[13], a13);           \
    a14 = fmaf(hk, (wk)[14], a14); a15 = fmaf(hk, (wk)[15], a15);

  int k = 0;
  #pragma unroll 2
  for (; k + 2 <= K; k += 2) {
    float hk0, hk1;
    if (FIRST) {
      hk0 = lds[lane * 33 + k];
      hk1 = lds[lane * 33 + k + 1];
    } else {
      float4 s = *(const float4*)&scsh[k];           // scsh[k],scsh[k+1]: 16B
      hk0 = fmaf(lds[k * HSTR + lane],       s.x, s.y);
      hk1 = fmaf(lds[(k + 1) * HSTR + lane], s.z, s.w);
    }
    const float* wk0 = Wt + (size_t)k * 64 + fbase;  // uniform -> s_load x16
    const float* wk1 = wk0 + 64;
    FMA16(hk0, wk0)
    FMA16(hk1, wk1)
  }
  { // tail (K odd)
    float hk;
    if (FIRST) {
      hk = lds[lane * 33 + k];
    } else {
      float2 s = scsh[k];
      hk = fmaf(lds[k * HSTR + lane], s.x, s.y);
    }
    const float* wk = Wt + (size_t)k * 64 + fbase;
    FMA16(hk, wk)
  }
  #undef FMA16

  // ---- ReLU + coalesced global stores (before barrier: overlap) ----
  a0=fmaxf(a0,0.f); a1=fmaxf(a1,0.f); a2=fmaxf(a2,0.f); a3=fmaxf(a3,0.f);
  a4=fmaxf(a4,0.f); a5=fmaxf(a5,0.f); a6=fmaxf(a6,0.f); a7=fmaxf(a7,0.f);
  a8=fmaxf(a8,0.f); a9=fmaxf(a9,0.f); a10=fmaxf(a10,0.f); a11=fmaxf(a11,0.f);
  a12=fmaxf(a12,0.f); a13=fmaxf(a13,0.f); a14=fmaxf(a14,0.f); a15=fmaxf(a15,0.f);

  float* op = hout + rowbase + lane;
  #define ST(j, aj) if (fbase + j < F) op[(size_t)(fbase + j) * B] = aj;
  ST(0,a0)  ST(1,a1)  ST(2,a2)  ST(3,a3)  ST(4,a4)  ST(5,a5)  ST(6,a6)  ST(7,a7)
  ST(8,a8)  ST(9,a9)  ST(10,a10) ST(11,a11) ST(12,a12) ST(13,a13) ST(14,a14) ST(15,a15)
  #undef ST

  __syncthreads();                      // all waves done reading hbuf

  // ---- per-wave y-tile (union with hbuf; wave-private, no extra barrier) ----
  float* ytq = lds + qu * (FPW * YSTR);
  ytq[0*YSTR+lane]=a0;   ytq[1*YSTR+lane]=a1;   ytq[2*YSTR+lane]=a2;
  ytq[3*YSTR+lane]=a3;   ytq[4*YSTR+lane]=a4;   ytq[5*YSTR+lane]=a5;
  ytq[6*YSTR+lane]=a6;   ytq[7*YSTR+lane]=a7;   ytq[8*YSTR+lane]=a8;
  ytq[9*YSTR+lane]=a9;   ytq[10*YSTR+lane]=a10; ytq[11*YSTR+lane]=a11;
  ytq[12*YSTR+lane]=a12; ytq[13*YSTR+lane]=a13; ytq[14*YSTR+lane]=a14;
  ytq[15*YSTR+lane]=a15;

  const int fl = lane >> 2, c = lane & 3;
  const float* yp = ytq + fl * YSTR + c * 16;        // 16B-aligned
  float4 v0 = *(const float4*)(yp);
  float4 v1 = *(const float4*)(yp + 4);
  float4 v2 = *(const float4*)(yp + 8);
  float4 v3 = *(const float4*)(yp + 12);
  float s1 = ((v0.x+v0.y)+(v0.z+v0.w)) + ((v1.x+v1.y)+(v1.z+v1.w))
           + ((v2.x+v2.y)+(v2.z+v2.w)) + ((v3.x+v3.y)+(v3.z+v3.w));
  float s2 = 0.f;
  s2 = fmaf(v0.x,v0.x,s2); s2 = fmaf(v0.y,v0.y,s2); s2 = fmaf(v0.z,v0.z,s2); s2 = fmaf(v0.w,v0.w,s2);
  s2 = fmaf(v1.x,v1.x,s2); s2 = fmaf(v1.y,v1.y,s2); s2 = fmaf(v1.z,v1.z,s2); s2 = fmaf(v1.w,v1.w,s2);
  s2 = fmaf(v2.x,v2.x,s2); s2 = fmaf(v2.y,v2.y,s2); s2 = fmaf(v2.z,v2.z,s2); s2 = fmaf(v2.w,v2.w,s2);
  s2 = fmaf(v3.x,v3.x,s2); s2 = fmaf(v3.y,v3.y,s2); s2 = fmaf(v3.z,v3.z,s2); s2 = fmaf(v3.w,v3.w,s2);

  s1 += __shfl_xor(s1, 1, 64);  s2 += __shfl_xor(s2, 1, 64);
  s1 += __shfl_xor(s1, 2, 64);  s2 += __shfl_xor(s2, 2, 64);

  if (c == 0 && fbase + fl < F) {
    double* slot = acc + ((size_t)(fbase + fl) * NSLC + slice) * 2;
    atomicAdd(slot,     (double)s1);                 // hw f64 atomic
    atomicAdd(slot + 1, (double)s2);
  }
}

// ---------------------------------------------------------------------------
// Final BN: hT -> row-major out. Wave 0 scsh || waves 1-3 stage raw hT;
// barrier; all threads write out with normalize inline.
// ---------------------------------------------------------------------------
__global__ void __launch_bounds__(NTHR, 8)
final_tr_kernel(const float* __restrict__ hT, const double* __restrict__ acc_last,
                const float* __restrict__ g, const float* __restrict__ bt,
                float* __restrict__ out)
{
  __shared__ float2 scsh[64];
  __shared__ float  ybuf[F * 64];                    // [j][64] raw
  const int tid  = threadIdx.x;
  const int lane = tid & 63;
  const int qu   = __builtin_amdgcn_readfirstlane(tid >> 6);
  const int rowbase = blockIdx.x * RPB;

  if (qu == 0) {
    scsh_wave0(acc_last, g, bt, scsh, lane);
  } else {
    for (int i = tid - 64; i < F * 16; i += (NTHR - 64)) {
      int j = i >> 4, r4 = i & 15;
      float4 v = *(const float4*)(hT + (size_t)j * B + rowbase + r4 * 4);
      *(float4*)&ybuf[j * 64 + r4 * 4] = v;
    }
  }
  __syncthreads();

  float* oblk = out + (size_t)rowbase * F;
  for (int i = tid; i < RPB * F; i += NTHR) {
    int r = i / F, j = i - r * F;
    float2 s = scsh[j];
    oblk[i] = fmaf(ybuf[j * 64 + r], s.x, s.y);
  }
}

// ---------------------------------------------------------------------------
extern "C" void kernel_launch(void* const* d_in, const int* in_sizes, int n_in,
                              void* d_out, int out_size, void* d_ws, size_t ws_size,
                              hipStream_t stream)
{
  const float* x   = (const float*)d_in[0];
  const float* W0  = (const float*)d_in[1];
  const float* b0  = (const float*)d_in[2];
  const float* g0  = (const float*)d_in[3];
  const float* bt0 = (const float*)d_in[4];
  const float* Ws  = (const float*)d_in[5];
  const float* bs  = (const float*)d_in[6];
  const float* gs  = (const float*)d_in[7];
  const float* bts = (const float*)d_in[8];
  float* out = (float*)d_out;

  double* acc = (double*)d_ws;                       // [NB][F][NSLC][2]
  float*  Wt  = (float*)((char*)d_ws + WT_OFF_B);    // [29+14*59][64]
  float*  hB  = (float*)((char*)d_ws + HB_OFF_B);    // [F][B] in workspace
  float*  hA  = out;                                 // [F][B] alias of d_out

  // zero the atomic accumulators every call (deterministic, capture-safe)
  hipMemsetAsync(d_ws, 0, (size_t)ACC_TOTAL * sizeof(double), stream);

  // transpose all 15 weight matrices (zero-padded to j<64)
  transpose_w<<<NB, NTHR, 0, stream>>>(W0, Ws, Wt);

  // layer 0: x[B,29] -> hB
  layer_kernel<K0, true><<<NBLK, NTHR, 0, stream>>>(
      x, Wt, b0, nullptr, nullptr, nullptr, hB, acc);

  // layers 1..14: ping-pong hB <-> hA (d_out), normalize-prev-on-read
  for (int b = 1; b < NB; ++b) {
    const float* gp  = (b == 1) ? g0  : gs  + (size_t)(b - 2) * F;
    const float* btp = (b == 1) ? bt0 : bts + (size_t)(b - 2) * F;
    const float* src = (b & 1) ? hB : hA;
    float*       dst = (b & 1) ? hA : hB;
    const float* Wtb = Wt + (size_t)K0 * 64 + (size_t)(b - 1) * F * 64;
    layer_kernel<F, false><<<NBLK, NTHR, 0, stream>>>(
        src, Wtb, bs + (size_t)(b - 1) * F,
        acc + (size_t)(b - 1) * ACC_PER_LAYER, gp, btp,
        dst, acc + (size_t)b * ACC_PER_LAYER);
  }

  // layer 14 wrote hB (b=14 even) -> final BN into row-major d_out
  final_tr_kernel<<<NBLK, NTHR, 0, stream>>>(
      hB, acc + (size_t)(NB - 1) * ACC_PER_LAYER,
      gs + (size_t)(NB - 2) * F, bts + (size_t)(NB - 2) * F, out);
}

// Round 15
// 463.117 us; speedup vs baseline: 8.5652x; 1.0027x over previous
//
#include <hip/hip_runtime.h>

#define NTHR  256
#define F     59
#define K0    29
#define NB    15
#define B     131072
#define RPB   64                 // rows per block (= wavefront size)
#define NBLK  (B / RPB)          // 2048 blocks
#define NSLC  32                 // f64 atomic slices; 16B slot per (feature,slice)
#define FPW   16                 // features per wave (16/16/16/11 real)
#define HSTR  68                 // hbuf row stride (272B: 16B-aligned rows)
#define YSTR  68                 // ytile feature stride
#define KC0   32                 // k-slots layer 0 (29 + 3 zero pad)
#define KCN   60                 // k-slots layers 1..14 (59 + 1 zero pad)

// d_ws: acc[NB][F][NSLC][2] dbl | Wt' | bp[15][64] f32 | hB[F][B] f32
#define ACC_PER_LAYER (F * NSLC * 2)
#define ACC_TOTAL     (NB * ACC_PER_LAYER)           // 453120 B
#define WT_OFF_B      ((size_t)ACC_TOTAL * 8)
#define WT0_FLOATS    (KC0 * 64)
#define WTN_FLOATS    (KCN * 64)
#define WT_FLOATS     (WT0_FLOATS + 14 * WTN_FLOATS) // 55808 floats
#define BP_OFF_B      (WT_OFF_B + (size_t)WT_FLOATS * 4)
#define HB_OFF_B      (BP_OFF_B + (size_t)NB * 64 * 4)

// ---------------------------------------------------------------------------
// Wt[k][j] = W[j][k], zero-padded to j<64 and k<KC. Layer 0 also copies b0.
// ---------------------------------------------------------------------------
__global__ void transpose_w(const float* __restrict__ W0, const float* __restrict__ b0,
                            const float* __restrict__ Ws,
                            float* __restrict__ Wt, float* __restrict__ bp0)
{
  const int b = blockIdx.x;
  if (b == 0) {
    for (int i = threadIdx.x; i < KC0 * 64; i += blockDim.x) {
      int k = i >> 6, j = i & 63;
      Wt[i] = (k < K0 && j < F) ? W0[j * K0 + k] : 0.f;
    }
    if (threadIdx.x < 64) bp0[threadIdx.x] = (threadIdx.x < F) ? b0[threadIdx.x] : 0.f;
  } else {
    float* dst = Wt + WT0_FLOATS + (size_t)(b - 1) * WTN_FLOATS;
    const float* W = Ws + (size_t)(b - 1) * F * F;
    for (int i = threadIdx.x; i < KCN * 64; i += blockDim.x) {
      int k = i >> 6, j = i & 63;
      dst[i] = (k < F && j < F) ? W[j * F + k] : 0.f;
    }
  }
}

// ---------------------------------------------------------------------------
// Fold BN(prev layer) into this layer's weights (in place) + bias:
//   W'[k][j] = Wt[k][j]*sc_k ;  b'[j] = b[j] + sum_k Wt[k][j]*sh_k (fp64).
// One block, 64 threads (j = lane). Column j read-then-written by one thread.
// ---------------------------------------------------------------------------
__global__ void fuse_w(const double* __restrict__ acc_prev,
                       const float* __restrict__ g, const float* __restrict__ bt,
                       const float* __restrict__ bias,
                       float* Wp, float* __restrict__ bp)
{
  __shared__ float  scf[64];
  __shared__ double shd[64];
  const int j = threadIdx.x;

  if (j < F) {
    const double* p = acc_prev + (size_t)j * (NSLC * 2);
    double s1 = 0.0, s2 = 0.0;
    #pragma unroll
    for (int s = 0; s < NSLC; ++s) { s1 += p[2 * s]; s2 += p[2 * s + 1]; }
    const double inv = 1.0 / (double)B;
    double mu   = s1 * inv;
    double var  = fma(s2, inv, -mu * mu);            // biased variance, fp64
    double rstd = 1.0 / sqrt(var + 1e-5);
    double sc   = rstd * (double)g[j];
    scf[j] = (float)sc;
    shd[j] = fma(-mu, sc, (double)bt[j]);
  } else { scf[j] = 0.f; shd[j] = 0.0; }
  __syncthreads();

  double bacc = (j < F) ? (double)bias[j] : 0.0;
  for (int k = 0; k < F; ++k) {                      // coalesced per k
    float w = Wp[k * 64 + j];
    bacc = fma((double)w, shd[k], bacc);
    Wp[k * 64 + j] = w * scf[k];
  }
  bp[j] = (float)bacc;
}

// ---------------------------------------------------------------------------
// scsh for the FINAL BN only (wave 0 of final_tr blocks).
// ---------------------------------------------------------------------------
__device__ __forceinline__ void scsh_wave0(const double* __restrict__ acc_prev,
                                           const float* __restrict__ g,
                                           const float* __restrict__ bt,
                                           float2* scsh, int lane)
{
  if (lane < F) {
    const double* p = acc_prev + (size_t)lane * (NSLC * 2);
    double s1 = 0.0, s2 = 0.0;
    #pragma unroll
    for (int s = 0; s < NSLC; ++s) { s1 += p[2 * s]; s2 += p[2 * s + 1]; }
    const double inv = 1.0 / (double)B;
    double mu   = s1 * inv;
    double var  = fma(s2, inv, -mu * mu);
    double rstd = 1.0 / sqrt(var + 1e-5);
    double sc   = rstd * (double)g[lane];
    scsh[lane] = make_float2((float)sc, (float)fma(-mu, sc, (double)bt[lane]));
  }
}

// ---------------------------------------------------------------------------
// One Linear+ReLU layer (BN pre-folded into Wp/bp). Block = 64 rows; wave q
// owns features 16q..16q+15. Stage raw h -> [r][68] (all 256 threads), then
// k-loop: 1 ds_read_b128 (own row) + 4x16 FMA per 4-k chunk; W via s_load.
// Epilogue: ReLU -> coalesced stores -> ytile -> 4x b128 + 2 shfl -> atomics.
// ---------------------------------------------------------------------------
template<int KC, bool FIRST>
__global__ void __launch_bounds__(NTHR, 8)
layer_kernel(const float* __restrict__ in, const float* __restrict__ Wp,
             const float* __restrict__ bp,
             float* __restrict__ hout, double* acc)
{
  __shared__ __attribute__((aligned(16))) float lds[4 * FPW * YSTR]; // 17408 B

  const int tid   = threadIdx.x;
  const int lane  = tid & 63;
  const int qu    = __builtin_amdgcn_readfirstlane(tid >> 6);
  const int rowbase = blockIdx.x * RPB;
  const int slice   = blockIdx.x & (NSLC - 1);

  // ---- stage raw h rows -> [r][HSTR], zero k-pad ----
  if (FIRST) {
    // x row-major [B][29]; k = i&31 (3 zero slots)
    for (int i = tid; i < RPB * KC0; i += NTHR) {
      int r = i >> 5, k = i & 31;
      lds[r * HSTR + k] = (k < K0) ? in[(size_t)(rowbase + r) * K0 + k] : 0.f;
    }
  } else {
    // hT [F][B]: float4 coalesced; k = 59 zero slot
    for (int i = tid; i < KCN * 16; i += NTHR) {
      int k = i >> 4, r4 = i & 15;
      float4 v = make_float4(0.f, 0.f, 0.f, 0.f);
      if (k < F) v = *(const float4*)(in + (size_t)k * B + rowbase + r4 * 4);
      lds[(4 * r4 + 0) * HSTR + k] = v.x;
      lds[(4 * r4 + 1) * HSTR + k] = v.y;
      lds[(4 * r4 + 2) * HSTR + k] = v.z;
      lds[(4 * r4 + 3) * HSTR + k] = v.w;
    }
  }
  __syncthreads();

  // ---- k-loop: own-row b128 h reads + s_load'd W' ----
  const int fbase = qu * FPW;
  const float* bq = bp + fbase;                      // uniform -> s_load
  float a0=bq[0],a1=bq[1],a2=bq[2],a3=bq[3],a4=bq[4],a5=bq[5],a6=bq[6],a7=bq[7],
        a8=bq[8],a9=bq[9],a10=bq[10],a11=bq[11],a12=bq[12],a13=bq[13],a14=bq[14],a15=bq[15];

  #define FMA16(hk, wk)                                                     \
    a0  = fmaf(hk, (wk)[0],  a0);  a1  = fmaf(hk, (wk)[1],  a1);            \
    a2  = fmaf(hk, (wk)[2],  a2);  a3  = fmaf(hk, (wk)[3],  a3);            \
    a4  = fmaf(hk, (wk)[4],  a4);  a5  = fmaf(hk, (wk)[5],  a5);            \
    a6  = fmaf(hk, (wk)[6],  a6);  a7  = fmaf(hk, (wk)[7],  a7);            \
    a8  = fmaf(hk, (wk)[8],  a8);  a9  = fmaf(hk, (wk)[9],  a9);            \
    a10 = fmaf(hk, (wk)[10], a10); a11 = fmaf(hk, (wk)[11], a11);           \
    a12 = fmaf(hk, (wk)[12], a12); a13 = fmaf(hk, (wk)[13], a13);           \
    a14 = fmaf(hk, (wk)[14], a14); a15 = fmaf(hk, (wk)[15], a15);

  const float* hrow = lds + lane * HSTR;
  #pragma unroll 3
  for (int c = 0; c < KC / 4; ++c) {
    float4 hv = *(const float4*)(hrow + 4 * c);      // 16B-aligned b128
    const float* wk = Wp + (size_t)(4 * c) * 64 + fbase;
    FMA16(hv.x, wk)
    FMA16(hv.y, wk + 64)
    FMA16(hv.z, wk + 128)
    FMA16(hv.w, wk + 192)
  }
  #undef FMA16

  // ---- ReLU + coalesced stores ----
  a0=fmaxf(a0,0.f); a1=fmaxf(a1,0.f); a2=fmaxf(a2,0.f); a3=fmaxf(a3,0.f);
  a4=fmaxf(a4,0.f); a5=fmaxf(a5,0.f); a6=fmaxf(a6,0.f); a7=fmaxf(a7,0.f);
  a8=fmaxf(a8,0.f); a9=fmaxf(a9,0.f); a10=fmaxf(a10,0.f); a11=fmaxf(a11,0.f);
  a12=fmaxf(a12,0.f); a13=fmaxf(a13,0.f); a14=fmaxf(a14,0.f); a15=fmaxf(a15,0.f);

  float* op = hout + rowbase + lane;
  #define ST(j, aj) if (fbase + j < F) op[(size_t)(fbase + j) * B] = aj;
  ST(0,a0)  ST(1,a1)  ST(2,a2)  ST(3,a3)  ST(4,a4)  ST(5,a5)  ST(6,a6)  ST(7,a7)
  ST(8,a8)  ST(9,a9)  ST(10,a10) ST(11,a11) ST(12,a12) ST(13,a13) ST(14,a14) ST(15,a15)
  #undef ST

  __syncthreads();                                   // hbuf dead, reuse as ytile

  // ---- per-wave y-tile reduction (R14-proven) ----
  float* ytq = lds + qu * (FPW * YSTR);
  ytq[0*YSTR+lane]=a0;   ytq[1*YSTR+lane]=a1;   ytq[2*YSTR+lane]=a2;
  ytq[3*YSTR+lane]=a3;   ytq[4*YSTR+lane]=a4;   ytq[5*YSTR+lane]=a5;
  ytq[6*YSTR+lane]=a6;   ytq[7*YSTR+lane]=a7;   ytq[8*YSTR+lane]=a8;
  ytq[9*YSTR+lane]=a9;   ytq[10*YSTR+lane]=a10; ytq[11*YSTR+lane]=a11;
  ytq[12*YSTR+lane]=a12; ytq[13*YSTR+lane]=a13; ytq[14*YSTR+lane]=a14;
  ytq[15*YSTR+lane]=a15;

  const int fl = lane >> 2, c = lane & 3;
  const float* yp = ytq + fl * YSTR + c * 16;
  float4 v0 = *(const float4*)(yp);
  float4 v1 = *(const float4*)(yp + 4);
  float4 v2 = *(const float4*)(yp + 8);
  float4 v3 = *(const float4*)(yp + 12);
  float s1 = ((v0.x+v0.y)+(v0.z+v0.w)) + ((v1.x+v1.y)+(v1.z+v1.w))
           + ((v2.x+v2.y)+(v2.z+v2.w)) + ((v3.x+v3.y)+(v3.z+v3.w));
  float s2 = 0.f;
  s2=fmaf(v0.x,v0.x,s2); s2=fmaf(v0.y,v0.y,s2); s2=fmaf(v0.z,v0.z,s2); s2=fmaf(v0.w,v0.w,s2);
  s2=fmaf(v1.x,v1.x,s2); s2=fmaf(v1.y,v1.y,s2); s2=fmaf(v1.z,v1.z,s2); s2=fmaf(v1.w,v1.w,s2);
  s2=fmaf(v2.x,v2.x,s2); s2=fmaf(v2.y,v2.y,s2); s2=fmaf(v2.z,v2.z,s2); s2=fmaf(v2.w,v2.w,s2);
  s2=fmaf(v3.x,v3.x,s2); s2=fmaf(v3.y,v3.y,s2); s2=fmaf(v3.z,v3.z,s2); s2=fmaf(v3.w,v3.w,s2);

  s1 += __shfl_xor(s1, 1, 64);  s2 += __shfl_xor(s2, 1, 64);
  s1 += __shfl_xor(s1, 2, 64);  s2 += __shfl_xor(s2, 2, 64);

  if (c == 0 && fbase + fl < F) {
    double* slot = acc + ((size_t)(fbase + fl) * NSLC + slice) * 2;
    atomicAdd(slot,     (double)s1);                 // hw f64 atomic
    atomicAdd(slot + 1, (double)s2);
  }
}

// ---------------------------------------------------------------------------
// Final BN: hT -> row-major out. Wave 0 scsh || waves 1-3 stage raw hT.
// ---------------------------------------------------------------------------
__global__ void __launch_bounds__(NTHR, 8)
final_tr_kernel(const float* __restrict__ hT, const double* __restrict__ acc_last,
                const float* __restrict__ g, const float* __restrict__ bt,
                float* __restrict__ out)
{
  __shared__ float2 scsh[64];
  __shared__ float  ybuf[F * 64];
  const int tid  = threadIdx.x;
  const int lane = tid & 63;
  const int qu   = __builtin_amdgcn_readfirstlane(tid >> 6);
  const int rowbase = blockIdx.x * RPB;

  if (qu == 0) {
    scsh_wave0(acc_last, g, bt, scsh, lane);
  } else {
    for (int i = tid - 64; i < F * 16; i += (NTHR - 64)) {
      int j = i >> 4, r4 = i & 15;
      float4 v = *(const float4*)(hT + (size_t)j * B + rowbase + r4 * 4);
      *(float4*)&ybuf[j * 64 + r4 * 4] = v;
    }
  }
  __syncthreads();

  float* oblk = out + (size_t)rowbase * F;
  for (int i = tid; i < RPB * F; i += NTHR) {
    int r = i / F, j = i - r * F;
    float2 s = scsh[j];
    oblk[i] = fmaf(ybuf[j * 64 + r], s.x, s.y);
  }
}

// ---------------------------------------------------------------------------
extern "C" void kernel_launch(void* const* d_in, const int* in_sizes, int n_in,
                              void* d_out, int out_size, void* d_ws, size_t ws_size,
                              hipStream_t stream)
{
  const float* x   = (const float*)d_in[0];
  const float* W0  = (const float*)d_in[1];
  const float* b0  = (const float*)d_in[2];
  const float* g0  = (const float*)d_in[3];
  const float* bt0 = (const float*)d_in[4];
  const float* Ws  = (const float*)d_in[5];
  const float* bs  = (const float*)d_in[6];
  const float* gs  = (const float*)d_in[7];
  const float* bts = (const float*)d_in[8];
  float* out = (float*)d_out;

  double* acc = (double*)d_ws;
  float*  Wt  = (float*)((char*)d_ws + WT_OFF_B);
  float*  bp  = (float*)((char*)d_ws + BP_OFF_B);    // [NB][64]
  float*  hB  = (float*)((char*)d_ws + HB_OFF_B);    // [F][B]
  float*  hA  = out;                                 // [F][B] alias of d_out

  hipMemsetAsync(d_ws, 0, (size_t)ACC_TOTAL * sizeof(double), stream);

  transpose_w<<<NB, NTHR, 0, stream>>>(W0, b0, Ws, Wt, bp);

  // layer 0: x -> hB  (no BN fold; raw weights)
  layer_kernel<KC0, true><<<NBLK, NTHR, 0, stream>>>(x, Wt, bp, hB, acc);

  // layers 1..14: fuse BN(prev) into weights, then layer
  for (int b = 1; b < NB; ++b) {
    const float* gp  = (b == 1) ? g0  : gs  + (size_t)(b - 2) * F;
    const float* btp = (b == 1) ? bt0 : bts + (size_t)(b - 2) * F;
    float* Wpb = Wt + WT0_FLOATS + (size_t)(b - 1) * WTN_FLOATS;
    fuse_w<<<1, 64, 0, stream>>>(acc + (size_t)(b - 1) * ACC_PER_LAYER,
                                 gp, btp, bs + (size_t)(b - 1) * F,
                                 Wpb, bp + (size_t)b * 64);
    const float* src = (b & 1) ? hB : hA;
    float*       dst = (b & 1) ? hA : hB;
    layer_kernel<KCN, false><<<NBLK, NTHR, 0, stream>>>(
        src, Wpb, bp + (size_t)b * 64, dst, acc + (size_t)b * ACC_PER_LAYER);
  }

  // layer 14 wrote hB -> final BN into row-major d_out
  final_tr_kernel<<<NBLK, NTHR, 0, stream>>>(
      hB, acc + (size_t)(NB - 1) * ACC_PER_LAYER,
      gs + (size_t)(NB - 2) * F, bts + (size_t)(NB - 2) * F, out);
}

// Round 16
// 430.962 us; speedup vs baseline: 9.2042x; 1.0746x over previous
//
#include <hip/hip_runtime.h>

#define NTHR  256
#define F     59
#define K0    29
#define NB    15
#define B     131072
#define RPB   64                 // rows per block (= wavefront size)
#define NBLK  (B / RPB)          // 2048 blocks
#define NSLC  32                 // f64 atomic slices; 16B slot per (feature,slice)
#define FPW   16                 // features per wave (16/16/16/11 real)
#define YSTR  66                 // ytile stride: writes conflict-free, reads ~2-4 way
#define KC0   32                 // Wt k-slots layer 0
#define KCN   60                 // Wt k-slots layers 1..14

// d_ws: acc[NB][F][NSLC][2] dbl | Wt' | bp[15][64] f32 | hB[F][B] f32
#define ACC_PER_LAYER (F * NSLC * 2)
#define ACC_TOTAL     (NB * ACC_PER_LAYER)           // 453120 B
#define WT_OFF_B      ((size_t)ACC_TOTAL * 8)
#define WT0_FLOATS    (KC0 * 64)
#define WTN_FLOATS    (KCN * 64)
#define WT_FLOATS     (WT0_FLOATS + 14 * WTN_FLOATS)
#define BP_OFF_B      (WT_OFF_B + (size_t)WT_FLOATS * 4)
#define HB_OFF_B      (BP_OFF_B + (size_t)NB * 64 * 4)

// ---------------------------------------------------------------------------
// Wt[k][j] = W[j][k], zero-padded to j<64, k<KC. Layer 0 also pads b0.
// ---------------------------------------------------------------------------
__global__ void transpose_w(const float* __restrict__ W0, const float* __restrict__ b0,
                            const float* __restrict__ Ws,
                            float* __restrict__ Wt, float* __restrict__ bp0)
{
  const int b = blockIdx.x;
  if (b == 0) {
    for (int i = threadIdx.x; i < KC0 * 64; i += blockDim.x) {
      int k = i >> 6, j = i & 63;
      Wt[i] = (k < K0 && j < F) ? W0[j * K0 + k] : 0.f;
    }
    if (threadIdx.x < 64) bp0[threadIdx.x] = (threadIdx.x < F) ? b0[threadIdx.x] : 0.f;
  } else {
    float* dst = Wt + WT0_FLOATS + (size_t)(b - 1) * WTN_FLOATS;
    const float* W = Ws + (size_t)(b - 1) * F * F;
    for (int i = threadIdx.x; i < KCN * 64; i += blockDim.x) {
      int k = i >> 6, j = i & 63;
      dst[i] = (k < F && j < F) ? W[j * F + k] : 0.f;
    }
  }
}

// ---------------------------------------------------------------------------
// Fold BN(prev) into this layer's weights (in place) + fp64 bias.
// ---------------------------------------------------------------------------
__global__ void fuse_w(const double* __restrict__ acc_prev,
                       const float* __restrict__ g, const float* __restrict__ bt,
                       const float* __restrict__ bias,
                       float* Wp, float* __restrict__ bp)
{
  __shared__ float  scf[64];
  __shared__ double shd[64];
  const int j = threadIdx.x;

  if (j < F) {
    const double* p = acc_prev + (size_t)j * (NSLC * 2);
    double s1 = 0.0, s2 = 0.0;
    #pragma unroll
    for (int s = 0; s < NSLC; ++s) { s1 += p[2 * s]; s2 += p[2 * s + 1]; }
    const double inv = 1.0 / (double)B;
    double mu   = s1 * inv;
    double var  = fma(s2, inv, -mu * mu);            // biased variance, fp64
    double rstd = 1.0 / sqrt(var + 1e-5);
    double sc   = rstd * (double)g[j];
    scf[j] = (float)sc;
    shd[j] = fma(-mu, sc, (double)bt[j]);
  } else { scf[j] = 0.f; shd[j] = 0.0; }
  __syncthreads();

  double bacc = (j < F) ? (double)bias[j] : 0.0;
  for (int k = 0; k < F; ++k) {
    float w = Wp[k * 64 + j];
    bacc = fma((double)w, shd[k], bacc);
    Wp[k * 64 + j] = w * scf[k];
  }
  bp[j] = (float)bacc;
}

// ---------------------------------------------------------------------------
// scsh for the FINAL BN (wave 0 of final_tr blocks).
// ---------------------------------------------------------------------------
__device__ __forceinline__ void scsh_wave0(const double* __restrict__ acc_prev,
                                           const float* __restrict__ g,
                                           const float* __restrict__ bt,
                                           float2* scsh, int lane)
{
  if (lane < F) {
    const double* p = acc_prev + (size_t)lane * (NSLC * 2);
    double s1 = 0.0, s2 = 0.0;
    #pragma unroll
    for (int s = 0; s < NSLC; ++s) { s1 += p[2 * s]; s2 += p[2 * s + 1]; }
    const double inv = 1.0 / (double)B;
    double mu   = s1 * inv;
    double var  = fma(s2, inv, -mu * mu);
    double rstd = 1.0 / sqrt(var + 1e-5);
    double sc   = rstd * (double)g[lane];
    scsh[lane] = make_float2((float)sc, (float)fma(-mu, sc, (double)bt[lane]));
  }
}

// ---------------------------------------------------------------------------
// One Linear+ReLU layer, BARRIER-FREE (non-first). Block = 64 rows; wave q
// owns features 16q..16q+15. Waves free-run:
//   k-loop: h[k][rowbase+lane] straight from global (coalesced 256B/wave;
//   waves share the window via L2) + s_load'd W' rows + 16 FMA per k.
//   Epilogue: ReLU -> coalesced stores -> wave-private ytile -> 4x b128 +
//   2 shfl -> sliced f64 atomics. FIRST layer stages x via LDS (2 barriers).
// ---------------------------------------------------------------------------
template<bool FIRST>
__global__ void __launch_bounds__(NTHR, 8)
layer_kernel(const float* __restrict__ in, const float* __restrict__ Wp,
             const float* __restrict__ bp,
             float* __restrict__ hout, double* acc)
{
  __shared__ __attribute__((aligned(16))) float lds[4 * FPW * YSTR]; // 16896 B

  const int tid   = threadIdx.x;
  const int lane  = tid & 63;
  const int qu    = __builtin_amdgcn_readfirstlane(tid >> 6);
  const int rowbase = blockIdx.x * RPB;
  const int slice   = blockIdx.x & (NSLC - 1);

  if (FIRST) {                                       // x row-major: LDS stage
    for (int i = tid; i < RPB * 33; i += NTHR) {
      int r = i / 33, k = i - r * 33;
      lds[i] = (k < K0) ? in[(size_t)(rowbase + r) * K0 + k] : 0.f;
    }
    __syncthreads();
  }

  const int fbase = qu * FPW;
  const float* bq = bp + fbase;                      // uniform -> s_load
  float a0=bq[0],a1=bq[1],a2=bq[2],a3=bq[3],a4=bq[4],a5=bq[5],a6=bq[6],a7=bq[7],
        a8=bq[8],a9=bq[9],a10=bq[10],a11=bq[11],a12=bq[12],a13=bq[13],a14=bq[14],a15=bq[15];

  #define FMA16(hk, wk)                                                     \
    a0  = fmaf(hk, (wk)[0],  a0);  a1  = fmaf(hk, (wk)[1],  a1);            \
    a2  = fmaf(hk, (wk)[2],  a2);  a3  = fmaf(hk, (wk)[3],  a3);            \
    a4  = fmaf(hk, (wk)[4],  a4);  a5  = fmaf(hk, (wk)[5],  a5);            \
    a6  = fmaf(hk, (wk)[6],  a6);  a7  = fmaf(hk, (wk)[7],  a7);            \
    a8  = fmaf(hk, (wk)[8],  a8);  a9  = fmaf(hk, (wk)[9],  a9);            \
    a10 = fmaf(hk, (wk)[10], a10); a11 = fmaf(hk, (wk)[11], a11);           \
    a12 = fmaf(hk, (wk)[12], a12); a13 = fmaf(hk, (wk)[13], a13);           \
    a14 = fmaf(hk, (wk)[14], a14); a15 = fmaf(hk, (wk)[15], a15);

  if (FIRST) {
    const float* hrow = lds + lane * 33;
    #pragma unroll 2
    for (int c = 0; c < 7; ++c) {                    // 28 k's
      float h0 = hrow[4*c], h1 = hrow[4*c+1], h2 = hrow[4*c+2], h3 = hrow[4*c+3];
      const float* wk = Wp + (size_t)(4 * c) * 64 + fbase;
      FMA16(h0, wk) FMA16(h1, wk + 64) FMA16(h2, wk + 128) FMA16(h3, wk + 192)
    }
    { float h28 = hrow[28];                          // tail k=28
      FMA16(h28, Wp + (size_t)28 * 64 + fbase) }
    __syncthreads();                                 // lds -> ytile reuse
  } else {
    const float* hcol = in + rowbase + lane;         // coalesced per wave
    #pragma unroll 2
    for (int c = 0; c < 14; ++c) {                   // 56 k's
      float h0 = hcol[(size_t)(4*c)   * B];
      float h1 = hcol[(size_t)(4*c+1) * B];
      float h2 = hcol[(size_t)(4*c+2) * B];
      float h3 = hcol[(size_t)(4*c+3) * B];
      const float* wk = Wp + (size_t)(4 * c) * 64 + fbase;
      FMA16(h0, wk) FMA16(h1, wk + 64) FMA16(h2, wk + 128) FMA16(h3, wk + 192)
    }
    { float h56 = hcol[(size_t)56 * B];              // tail 56..58
      float h57 = hcol[(size_t)57 * B];
      float h58 = hcol[(size_t)58 * B];
      const float* wk = Wp + (size_t)56 * 64 + fbase;
      FMA16(h56, wk) FMA16(h57, wk + 64) FMA16(h58, wk + 128) }
  }
  #undef FMA16

  // ---- ReLU + coalesced stores ----
  a0=fmaxf(a0,0.f); a1=fmaxf(a1,0.f); a2=fmaxf(a2,0.f); a3=fmaxf(a3,0.f);
  a4=fmaxf(a4,0.f); a5=fmaxf(a5,0.f); a6=fmaxf(a6,0.f); a7=fmaxf(a7,0.f);
  a8=fmaxf(a8,0.f); a9=fmaxf(a9,0.f); a10=fmaxf(a10,0.f); a11=fmaxf(a11,0.f);
  a12=fmaxf(a12,0.f); a13=fmaxf(a13,0.f); a14=fmaxf(a14,0.f); a15=fmaxf(a15,0.f);

  float* op = hout + rowbase + lane;
  #define ST(j, aj) if (fbase + j < F) op[(size_t)(fbase + j) * B] = aj;
  ST(0,a0)  ST(1,a1)  ST(2,a2)  ST(3,a3)  ST(4,a4)  ST(5,a5)  ST(6,a6)  ST(7,a7)
  ST(8,a8)  ST(9,a9)  ST(10,a10) ST(11,a11) ST(12,a12) ST(13,a13) ST(14,a14) ST(15,a15)
  #undef ST

  // ---- wave-private ytile stats (no barrier: intra-wave DS ordering) ----
  float* ytq = lds + qu * (FPW * YSTR);
  ytq[0*YSTR+lane]=a0;   ytq[1*YSTR+lane]=a1;   ytq[2*YSTR+lane]=a2;
  ytq[3*YSTR+lane]=a3;   ytq[4*YSTR+lane]=a4;   ytq[5*YSTR+lane]=a5;
  ytq[6*YSTR+lane]=a6;   ytq[7*YSTR+lane]=a7;   ytq[8*YSTR+lane]=a8;
  ytq[9*YSTR+lane]=a9;   ytq[10*YSTR+lane]=a10; ytq[11*YSTR+lane]=a11;
  ytq[12*YSTR+lane]=a12; ytq[13*YSTR+lane]=a13; ytq[14*YSTR+lane]=a14;
  ytq[15*YSTR+lane]=a15;

  const int fl = lane >> 2, c = lane & 3;
  const float* yp = ytq + fl * YSTR + c * 16;
  float4 v0 = *(const float4*)(yp);
  float4 v1 = *(const float4*)(yp + 4);
  float4 v2 = *(const float4*)(yp + 8);
  float4 v3 = *(const float4*)(yp + 12);
  float s1 = ((v0.x+v0.y)+(v0.z+v0.w)) + ((v1.x+v1.y)+(v1.z+v1.w))
           + ((v2.x+v2.y)+(v2.z+v2.w)) + ((v3.x+v3.y)+(v3.z+v3.w));
  float s2 = 0.f;
  s2=fmaf(v0.x,v0.x,s2); s2=fmaf(v0.y,v0.y,s2); s2=fmaf(v0.z,v0.z,s2); s2=fmaf(v0.w,v0.w,s2);
  s2=fmaf(v1.x,v1.x,s2); s2=fmaf(v1.y,v1.y,s2); s2=fmaf(v1.z,v1.z,s2); s2=fmaf(v1.w,v1.w,s2);
  s2=fmaf(v2.x,v2.x,s2); s2=fmaf(v2.y,v2.y,s2); s2=fmaf(v2.z,v2.z,s2); s2=fmaf(v2.w,v2.w,s2);
  s2=fmaf(v3.x,v3.x,s2); s2=fmaf(v3.y,v3.y,s2); s2=fmaf(v3.z,v3.z,s2); s2=fmaf(v3.w,v3.w,s2);

  s1 += __shfl_xor(s1, 1, 64);  s2 += __shfl_xor(s2, 1, 64);
  s1 += __shfl_xor(s1, 2, 64);  s2 += __shfl_xor(s2, 2, 64);

  if (c == 0 && fbase + fl < F) {
    double* slot = acc + ((size_t)(fbase + fl) * NSLC + slice) * 2;
    atomicAdd(slot,     (double)s1);                 // hw f64 atomic
    atomicAdd(slot + 1, (double)s2);
  }
}

// ---------------------------------------------------------------------------
// Final BN: hT -> row-major out. Wave 0 scsh || waves 1-3 stage raw hT.
// ---------------------------------------------------------------------------
__global__ void __launch_bounds__(NTHR, 8)
final_tr_kernel(const float* __restrict__ hT, const double* __restrict__ acc_last,
                const float* __restrict__ g, const float* __restrict__ bt,
                float* __restrict__ out)
{
  __shared__ float2 scsh[64];
  __shared__ float  ybuf[F * 64];
  const int tid  = threadIdx.x;
  const int lane = tid & 63;
  const int qu   = __builtin_amdgcn_readfirstlane(tid >> 6);
  const int rowbase = blockIdx.x * RPB;

  if (qu == 0) {
    scsh_wave0(acc_last, g, bt, scsh, lane);
  } else {
    for (int i = tid - 64; i < F * 16; i += (NTHR - 64)) {
      int j = i >> 4, r4 = i & 15;
      float4 v = *(const float4*)(hT + (size_t)j * B + rowbase + r4 * 4);
      *(float4*)&ybuf[j * 64 + r4 * 4] = v;
    }
  }
  __syncthreads();

  float* oblk = out + (size_t)rowbase * F;
  for (int i = tid; i < RPB * F; i += NTHR) {
    int r = i / F, j = i - r * F;
    float2 s = scsh[j];
    oblk[i] = fmaf(ybuf[j * 64 + r], s.x, s.y);
  }
}

// ---------------------------------------------------------------------------
extern "C" void kernel_launch(void* const* d_in, const int* in_sizes, int n_in,
                              void* d_out, int out_size, void* d_ws, size_t ws_size,
                              hipStream_t stream)
{
  const float* x   = (const float*)d_in[0];
  const float* W0  = (const float*)d_in[1];
  const float* b0  = (const float*)d_in[2];
  const float* g0  = (const float*)d_in[3];
  const float* bt0 = (const float*)d_in[4];
  const float* Ws  = (const float*)d_in[5];
  const float* bs  = (const float*)d_in[6];
  const float* gs  = (const float*)d_in[7];
  const float* bts = (const float*)d_in[8];
  float* out = (float*)d_out;

  double* acc = (double*)d_ws;
  float*  Wt  = (float*)((char*)d_ws + WT_OFF_B);
  float*  bp  = (float*)((char*)d_ws + BP_OFF_B);    // [NB][64]
  float*  hB  = (float*)((char*)d_ws + HB_OFF_B);    // [F][B]
  float*  hA  = out;                                 // [F][B] alias of d_out

  hipMemsetAsync(d_ws, 0, (size_t)ACC_TOTAL * sizeof(double), stream);

  transpose_w<<<NB, NTHR, 0, stream>>>(W0, b0, Ws, Wt, bp);

  // layer 0: x -> hB (raw weights)
  layer_kernel<true><<<NBLK, NTHR, 0, stream>>>(x, Wt, bp, hB, acc);

  // layers 1..14: fuse BN(prev) into weights, then barrier-free layer
  for (int b = 1; b < NB; ++b) {
    const float* gp  = (b == 1) ? g0  : gs  + (size_t)(b - 2) * F;
    const float* btp = (b == 1) ? bt0 : bts + (size_t)(b - 2) * F;
    float* Wpb = Wt + WT0_FLOATS + (size_t)(b - 1) * WTN_FLOATS;
    fuse_w<<<1, 64, 0, stream>>>(acc + (size_t)(b - 1) * ACC_PER_LAYER,
                                 gp, btp, bs + (size_t)(b - 1) * F,
                                 Wpb, bp + (size_t)b * 64);
    const float* src = (b & 1) ? hB : hA;
    float*       dst = (b & 1) ? hA : hB;
    layer_kernel<false><<<NBLK, NTHR, 0, stream>>>(
        src, Wpb, bp + (size_t)b * 64, dst, acc + (size_t)b * ACC_PER_LAYER);
  }

  // layer 14 wrote hB -> final BN into row-major d_out
  final_tr_kernel<<<NBLK, NTHR, 0, stream>>>(
      hB, acc + (size_t)(NB - 1) * ACC_PER_LAYER,
      gs + (size_t)(NB - 2) * F, bts + (size_t)(NB - 2) * F, out);
}